// Round 3
// baseline (182.479 us; speedup 1.0000x reference)
//
#include <hip/hip_runtime.h>
#include <hip/hip_bf16.h>
#include <stdint.h>

#define TT 8192
#define MM 64
#define CHUNK 32                  // output timesteps per block
#define WQ 96                     // Q warmup steps (0.9^96 ~ 4e-5)
#define WS 32                     // sigma warmup on top of WQ (0.25^32 ~ 5e-20)
#define YROWS (CHUNK + WQ + WS)   // 160 staged y rows (reused for ustd rows)

__global__ __launch_bounds__(256, 2)
void dcc_kernel(const float* __restrict__ y, const float* __restrict__ MU,
                const float* __restrict__ sigma0, const float* __restrict__ alpha0,
                const float* __restrict__ alpha, const float* __restrict__ beta,
                const float* __restrict__ L0, const float* __restrict__ Ap,
                const float* __restrict__ Bp,
                float* __restrict__ out)
{
    // lds_yu: first holds y rows [ts0,cend); ustd rows overwrite from the front.
    // Safe: ustd row (t - tq0) is written only after y row (t - ts0) is read,
    // and t - tq0 <= t - ts0 (each thread owns its column m exclusively).
    __shared__ float lds_yu[YROWS][MM];   // 40 KB
    __shared__ float lds_s[CHUNK][MM];    // 8 KB

    const int tid  = threadIdx.x;
    const int c0   = blockIdx.x * CHUNK;
    const int cend = c0 + CHUNK;
    const int tq0  = (c0 > WQ) ? (c0 - WQ) : 0;
    const int ts0  = (tq0 > WS) ? (tq0 - WS) : 0;

    const float A = Ap[0], B = Bp[0];
    const float kappa = 1.0f - A - B;

    float* out_mu = out;                         // T*M floats
    float* out_sg = out + (size_t)TT * MM;       // T*M*M floats

    // ---- phase 0a: mus chunk = exact copy of MU, broadcast over 32 rows ----
    {
        int o = tid * 8;              // 256*8 = 2048 = CHUNK*MM elements
        int m = o & (MM - 1);         // multiple of 8 -> 16B-aligned
        float4 a = *(const float4*)(MU + m);
        float4 b = *(const float4*)(MU + m + 4);
        float* dst = out_mu + (size_t)c0 * MM + o;
        *(float4*)(dst)     = a;
        *(float4*)(dst + 4) = b;
    }

    // ---- phase 0b: stage y rows [ts0, cend) into LDS (coalesced f32x4) ----
    {
        const float* ysrc = y + (size_t)ts0 * MM;
        const int nflt = (cend - ts0) * MM;           // <= 10240
        for (int o = tid * 4; o < nflt; o += 256 * 4) {
            float4 v = *(const float4*)(ysrc + o);
            *(float4*)(&lds_yu[0][0] + o) = v;
        }
    }
    __syncthreads();

    // ---- phase 1b: sigma recursion (wave 0 only; serial critical path) ----
    if (tid < MM) {
        const int m = tid;
        const float mu  = MU[m];
        const float al  = alpha[m], be = beta[m];
        const float a0v = alpha0[m] * alpha0[m];
        float s2 = sigma0[m] * sigma0[m];          // exact init when ts0==0
        float u_prev = (ts0 > 0) ? (y[(size_t)(ts0 - 1) * MM + m] - mu) : 0.0f;
        for (int t = ts0; t < cend; ++t) {
            float yt  = lds_yu[t - ts0][m];                            // read y first
            float s2n = fmaf(al, s2, fmaf(be, u_prev * u_prev, a0v));  // sig_t^2
            if (t >= tq0) lds_yu[t - tq0][m] = u_prev * rsqrtf(s2);    // ustd_t
            if (t >= c0)  lds_s[t - c0][m]   = sqrtf(s2n);             // sig_t
            u_prev = yt - mu;
            s2 = s2n;
        }
    }

    // ---- phase 1a: per-thread 4x4 tile of A0 = L0^T L0 (+ diag sums) ----
    // (other 3 waves run this while wave 0 is in phase 1b)
    const int j0 = (tid & 15) * 4;
    const int i0 = (tid >> 4) * 4;

    float acc[4][4], adr[4], adc[4];
    #pragma unroll
    for (int a = 0; a < 4; ++a) {
        adr[a] = 0.f; adc[a] = 0.f;
        #pragma unroll
        for (int b = 0; b < 4; ++b) acc[a][b] = 0.f;
    }
    #pragma unroll 4
    for (int k = 0; k < MM; ++k) {
        float4 Li = *(const float4*)(L0 + k * MM + i0);
        float4 Lj = *(const float4*)(L0 + k * MM + j0);
        float li[4] = {Li.x, Li.y, Li.z, Li.w};
        float lj[4] = {Lj.x, Lj.y, Lj.z, Lj.w};
        #pragma unroll
        for (int a = 0; a < 4; ++a) {
            #pragma unroll
            for (int b = 0; b < 4; ++b)
                acc[a][b] = fmaf(li[a], lj[b], acc[a][b]);
            adr[a] = fmaf(li[a], li[a], adr[a]);
            adc[a] = fmaf(lj[a], lj[a], adc[a]);
        }
    }
    __syncthreads();

    // ---- phase 2: Q recurrence on 4x4 tile + replicated diag recurrences ----
    float q[4][4], Cm[4][4], qdr[4], qdc[4], Cdr[4], Cdc[4];
    #pragma unroll
    for (int a = 0; a < 4; ++a) {
        qdr[a] = adr[a]; Cdr[a] = kappa * adr[a];
        qdc[a] = adc[a]; Cdc[a] = kappa * adc[a];
        #pragma unroll
        for (int b = 0; b < 4; ++b) {
            q[a][b]  = acc[a][b];            // Q init = A0 (exact for tq0==0)
            Cm[a][b] = kappa * acc[a][b];
        }
    }

    for (int t = tq0; t < cend; ++t) {
        const int r = t - tq0;
        float4 U_i = *(const float4*)(&lds_yu[r][i0]);
        float4 U_j = *(const float4*)(&lds_yu[r][j0]);
        float ui[4] = {U_i.x, U_i.y, U_i.z, U_i.w};
        float uj[4] = {U_j.x, U_j.y, U_j.z, U_j.w};
        #pragma unroll
        for (int a = 0; a < 4; ++a) {
            float bui = B * ui[a];
            #pragma unroll
            for (int b = 0; b < 4; ++b)
                q[a][b] = fmaf(A, q[a][b], fmaf(bui, uj[b], Cm[a][b]));
            qdr[a] = fmaf(A, qdr[a], fmaf(bui, ui[a], Cdr[a]));
            float buj = B * uj[a];
            qdc[a] = fmaf(A, qdc[a], fmaf(buj, uj[a], Cdc[a]));
        }
        if (t >= c0) {   // wave-uniform branch
            float4 S_i = *(const float4*)(&lds_s[t - c0][i0]);
            float4 S_j = *(const float4*)(&lds_s[t - c0][j0]);
            float ri[4] = { S_i.x * rsqrtf(qdr[0]), S_i.y * rsqrtf(qdr[1]),
                            S_i.z * rsqrtf(qdr[2]), S_i.w * rsqrtf(qdr[3]) };
            float rj[4] = { S_j.x * rsqrtf(qdc[0]), S_j.y * rsqrtf(qdc[1]),
                            S_j.z * rsqrtf(qdc[2]), S_j.w * rsqrtf(qdc[3]) };
            float* o = out_sg + ((size_t)t << 12) + (i0 << 6) + j0;
            #pragma unroll
            for (int a = 0; a < 4; ++a) {
                float f = ri[a];
                float4 w;
                w.x = q[a][0] * f * rj[0];
                w.y = q[a][1] * f * rj[1];
                w.z = q[a][2] * f * rj[2];
                w.w = q[a][3] * f * rj[3];
                *(float4*)(o + a * MM) = w;
            }
        }
    }
}

extern "C" void kernel_launch(void* const* d_in, const int* in_sizes, int n_in,
                              void* d_out, int out_size, void* d_ws, size_t ws_size,
                              hipStream_t stream) {
    (void)in_sizes; (void)n_in; (void)out_size; (void)d_ws; (void)ws_size;
    const float* y      = (const float*)d_in[0];
    const float* MU     = (const float*)d_in[1];
    const float* sigma0 = (const float*)d_in[2];
    const float* alpha0 = (const float*)d_in[3];
    const float* alpha  = (const float*)d_in[4];
    const float* beta   = (const float*)d_in[5];
    const float* L0     = (const float*)d_in[6];
    const float* A      = (const float*)d_in[7];
    const float* B      = (const float*)d_in[8];
    dcc_kernel<<<dim3(TT / CHUNK), dim3(256), 0, stream>>>(
        y, MU, sigma0, alpha0, alpha, beta, L0, A, B, (float*)d_out);
}

// Round 4
// 170.962 us; speedup vs baseline: 1.0674x; 1.0674x over previous
//
#include <hip/hip_runtime.h>
#include <hip/hip_bf16.h>
#include <stdint.h>

#define TT 8192
#define MM 64
#define CHUNK 32                  // output timesteps per chunk
#define WQ 64                     // Q warmup steps (0.9^64 ~ 1.2e-3 decay)
#define WS 16                     // sigma warmup on top of WQ (0.25^16 ~ 2e-10)
#define YROWS (CHUNK + WQ + WS)   // 112 staged y rows (reused for ustd rows)
#define NSPLIT 2                  // row-split of the 64x64 tile across blocks

__global__ __launch_bounds__(256, 2)
void dcc_kernel(const float* __restrict__ y, const float* __restrict__ MU,
                const float* __restrict__ sigma0, const float* __restrict__ alpha0,
                const float* __restrict__ alpha, const float* __restrict__ beta,
                const float* __restrict__ L0, const float* __restrict__ Ap,
                const float* __restrict__ Bp,
                float* __restrict__ out)
{
    // lds_yu: first holds y rows [ts0,cend); ustd rows overwrite from the front.
    // Safe: ustd row (t - tq0) is written only after y row (t - ts0) is read,
    // and t - tq0 <= t - ts0 (each thread owns its column m exclusively).
    __shared__ float lds_yu[YROWS][MM];   // 28 KB
    __shared__ float lds_s[CHUNK][MM];    // 8 KB

    const int tid  = threadIdx.x;
    const int chnk = blockIdx.x >> 1;          // which time chunk
    const int h    = blockIdx.x & 1;           // which 32-row half of Sigma
    const int c0   = chnk * CHUNK;
    const int cend = c0 + CHUNK;
    const int tq0  = (c0 > WQ) ? (c0 - WQ) : 0;
    const int ts0  = (tq0 > WS) ? (tq0 - WS) : 0;

    const float A = Ap[0], B = Bp[0];
    const float kappa = 1.0f - A - B;

    float* out_mu = out;                         // T*M floats
    float* out_sg = out + (size_t)TT * MM;       // T*M*M floats

    // ---- phase 0a: mus chunk = exact copy of MU (h==0 blocks only) ----
    if (h == 0) {
        int o = tid * 8;              // 256*8 = 2048 = CHUNK*MM elements
        int m = o & (MM - 1);
        float4 a = *(const float4*)(MU + m);
        float4 b = *(const float4*)(MU + m + 4);
        float* dst = out_mu + (size_t)c0 * MM + o;
        *(float4*)(dst)     = a;
        *(float4*)(dst + 4) = b;
    }

    // ---- phase 0b: stage y rows [ts0, cend) into LDS (coalesced f32x4) ----
    {
        const float* ysrc = y + (size_t)ts0 * MM;
        const int nflt = (cend - ts0) * MM;           // <= 7168
        for (int o = tid * 4; o < nflt; o += 256 * 4) {
            float4 v = *(const float4*)(ysrc + o);
            *(float4*)(&lds_yu[0][0] + o) = v;
        }
    }
    __syncthreads();

    // ---- phase 1b: sigma recursion (wave 0 only; serial critical path) ----
    if (tid < MM) {
        const int m = tid;
        const float mu  = MU[m];
        const float al  = alpha[m], be = beta[m];
        const float a0v = alpha0[m] * alpha0[m];
        float s2 = sigma0[m] * sigma0[m];          // exact init when ts0==0
        float u_prev = (ts0 > 0) ? (y[(size_t)(ts0 - 1) * MM + m] - mu) : 0.0f;
        for (int t = ts0; t < cend; ++t) {
            float yt  = lds_yu[t - ts0][m];                            // read y first
            float s2n = fmaf(al, s2, fmaf(be, u_prev * u_prev, a0v));  // sig_t^2
            if (t >= tq0) lds_yu[t - tq0][m] = u_prev * rsqrtf(s2);    // ustd_t
            if (t >= c0)  lds_s[t - c0][m]   = sqrtf(s2n);             // sig_t
            u_prev = yt - mu;
            s2 = s2n;
        }
    }

    // ---- phase 1a: per-thread 2x4 tile of A0 = L0^T L0 (+ diag sums) ----
    // rows i0..i0+1 (within this block's 32-row half), cols j0..j0+3
    const int j0 = (tid & 15) * 4;
    const int i0 = h * 32 + (tid >> 4) * 2;

    float acc[2][4], adr[2], adc[4];
    #pragma unroll
    for (int a = 0; a < 2; ++a) { adr[a] = 0.f; }
    #pragma unroll
    for (int b = 0; b < 4; ++b) { adc[b] = 0.f; }
    #pragma unroll
    for (int a = 0; a < 2; ++a)
        #pragma unroll
        for (int b = 0; b < 4; ++b) acc[a][b] = 0.f;

    #pragma unroll 4
    for (int k = 0; k < MM; ++k) {
        float2 Li = *(const float2*)(L0 + k * MM + i0);
        float4 Lj = *(const float4*)(L0 + k * MM + j0);
        float li[2] = {Li.x, Li.y};
        float lj[4] = {Lj.x, Lj.y, Lj.z, Lj.w};
        #pragma unroll
        for (int a = 0; a < 2; ++a) {
            #pragma unroll
            for (int b = 0; b < 4; ++b)
                acc[a][b] = fmaf(li[a], lj[b], acc[a][b]);
            adr[a] = fmaf(li[a], li[a], adr[a]);
        }
        #pragma unroll
        for (int b = 0; b < 4; ++b)
            adc[b] = fmaf(lj[b], lj[b], adc[b]);
    }
    __syncthreads();

    // ---- phase 2: Q recurrence on 2x4 tile + replicated diag recurrences ----
    float q[2][4], Cm[2][4], qdr[2], qdc[4], Cdr[2], Cdc[4];
    #pragma unroll
    for (int a = 0; a < 2; ++a) { qdr[a] = adr[a]; Cdr[a] = kappa * adr[a]; }
    #pragma unroll
    for (int b = 0; b < 4; ++b) { qdc[b] = adc[b]; Cdc[b] = kappa * adc[b]; }
    #pragma unroll
    for (int a = 0; a < 2; ++a)
        #pragma unroll
        for (int b = 0; b < 4; ++b) {
            q[a][b]  = acc[a][b];            // Q init = A0 (exact for tq0==0)
            Cm[a][b] = kappa * acc[a][b];
        }

    for (int t = tq0; t < cend; ++t) {
        const int r = t - tq0;
        float2 U_i = *(const float2*)(&lds_yu[r][i0]);
        float4 U_j = *(const float4*)(&lds_yu[r][j0]);
        float ui[2] = {U_i.x, U_i.y};
        float uj[4] = {U_j.x, U_j.y, U_j.z, U_j.w};
        #pragma unroll
        for (int a = 0; a < 2; ++a) {
            float bui = B * ui[a];
            #pragma unroll
            for (int b = 0; b < 4; ++b)
                q[a][b] = fmaf(A, q[a][b], fmaf(bui, uj[b], Cm[a][b]));
            qdr[a] = fmaf(A, qdr[a], fmaf(bui, ui[a], Cdr[a]));
        }
        #pragma unroll
        for (int b = 0; b < 4; ++b) {
            float buj = B * uj[b];
            qdc[b] = fmaf(A, qdc[b], fmaf(buj, uj[b], Cdc[b]));
        }
        if (t >= c0) {   // wave-uniform branch
            float2 S_i = *(const float2*)(&lds_s[t - c0][i0]);
            float4 S_j = *(const float4*)(&lds_s[t - c0][j0]);
            float ri[2] = { S_i.x * rsqrtf(qdr[0]), S_i.y * rsqrtf(qdr[1]) };
            float rj[4] = { S_j.x * rsqrtf(qdc[0]), S_j.y * rsqrtf(qdc[1]),
                            S_j.z * rsqrtf(qdc[2]), S_j.w * rsqrtf(qdc[3]) };
            float* o = out_sg + ((size_t)t << 12) + (i0 << 6) + j0;
            #pragma unroll
            for (int a = 0; a < 2; ++a) {
                float f = ri[a];
                float4 w;
                w.x = q[a][0] * f * rj[0];
                w.y = q[a][1] * f * rj[1];
                w.z = q[a][2] * f * rj[2];
                w.w = q[a][3] * f * rj[3];
                *(float4*)(o + a * MM) = w;
            }
        }
    }
}

extern "C" void kernel_launch(void* const* d_in, const int* in_sizes, int n_in,
                              void* d_out, int out_size, void* d_ws, size_t ws_size,
                              hipStream_t stream) {
    (void)in_sizes; (void)n_in; (void)out_size; (void)d_ws; (void)ws_size;
    const float* y      = (const float*)d_in[0];
    const float* MU     = (const float*)d_in[1];
    const float* sigma0 = (const float*)d_in[2];
    const float* alpha0 = (const float*)d_in[3];
    const float* alpha  = (const float*)d_in[4];
    const float* beta   = (const float*)d_in[5];
    const float* L0     = (const float*)d_in[6];
    const float* A      = (const float*)d_in[7];
    const float* B      = (const float*)d_in[8];
    dcc_kernel<<<dim3((TT / CHUNK) * NSPLIT), dim3(256), 0, stream>>>(
        y, MU, sigma0, alpha0, alpha, beta, L0, A, B, (float*)d_out);
}